// Round 1
// baseline (245.756 us; speedup 1.0000x reference)
//
#include <hip/hip_runtime.h>
#include <cmath>

#define BB 4
#define CC 64
#define HH 64
#define WW 64
#define NN 52      // number of sampling points
#define NF 32      // 2*f_num offset channels (f branch)
#define NCC 72     // 2*c_num offset channels (c branch)
#define NM 53      // N+1 mask channels

// ---------------- NCHW -> NHWC transpose (LDS tiled) ----------------
__global__ __launch_bounds__(256) void transpose_kernel(const float* __restrict__ x,
                                                        float* __restrict__ xt) {
    int bid = blockIdx.x;           // one block per (b, y) row
    int b = bid >> 6, y = bid & 63;
    __shared__ float tile[64][65];  // [c][w], padded
    const float* xp = x + ((size_t)b * CC * HH + y) * WW;   // x[b, c, y, w] = xp[c*H*W + w]
    #pragma unroll
    for (int k = 0; k < 16; ++k) {
        int idx = threadIdx.x + (k << 8);
        int c = idx >> 6, w = idx & 63;
        tile[c][w] = xp[(size_t)c * HH * WW + w];
    }
    __syncthreads();
    float* op = xt + ((size_t)(b * HH + y) * WW) * CC;       // xt[(b,y,w), c]
    #pragma unroll
    for (int k = 0; k < 16; ++k) {
        int idx = threadIdx.x + (k << 8);
        int w = idx >> 6, c = idx & 63;
        op[(size_t)w * CC + c] = tile[c][w];
    }
}

// ---------------- fused main kernel: one wave (64 threads) per pixel ----------------
__global__ __launch_bounds__(64) void crossd_main(
    const float* __restrict__ xt, const float* __restrict__ p_n,
    const float* __restrict__ dwf_w, const float* __restrict__ dwf_b,
    const float* __restrict__ pwf_w, const float* __restrict__ pwf_b,
    const float* __restrict__ dwc_w, const float* __restrict__ dwc_b,
    const float* __restrict__ pwc_w, const float* __restrict__ pwc_b,
    const float* __restrict__ dwm_w, const float* __restrict__ dwm_b,
    const float* __restrict__ pwm_w, const float* __restrict__ pwm_b,
    const float* __restrict__ pc_w, const float* __restrict__ pc_b,
    const float* __restrict__ mlp_w1, const float* __restrict__ mlp_b1,
    const float* __restrict__ mlp_w2, const float* __restrict__ mlp_b2,
    float* __restrict__ out)
{
    const int pix = blockIdx.x;        // 0 .. B*H*W-1
    const int b  = pix >> 12;
    const int y  = (pix >> 6) & 63;
    const int xw = pix & 63;
    const int c  = threadIdx.x;        // lane = channel

    __shared__ float t_s[3][65];       // depthwise outputs (f, c, m branches), padded
    __shared__ float off_s[NF + NCC];  // 104 offset values (ch 0..51 = x-comp, 52..103 = y-comp)
    __shared__ float m_s[NM];          // 53 mask values
    __shared__ float mod_s[NN];        // softmax modulation
    __shared__ float va[64], vb[64];   // matvec ping-pong

    const float* xtb = xt + (size_t)b * HH * WW * CC;

    // ---- depthwise 3x3 (cross-correlation, zero pad), 3 branches ----
    float sf = dwf_b[c], scv = dwc_b[c], smv = dwm_b[c];
    #pragma unroll
    for (int dy = 0; dy < 3; ++dy) {
        int yy = y + dy - 1;
        if (yy < 0 || yy >= HH) continue;
        #pragma unroll
        for (int dx = 0; dx < 3; ++dx) {
            int xx = xw + dx - 1;
            if (xx < 0 || xx >= WW) continue;
            float v = xtb[((size_t)(yy * WW + xx)) * CC + c];
            int k = dy * 3 + dx;
            sf  = fmaf(v, dwf_w[c * 9 + k], sf);
            scv = fmaf(v, dwc_w[c * 9 + k], scv);
            smv = fmaf(v, dwm_w[c * 9 + k], smv);
        }
    }
    t_s[0][c] = sf; t_s[1][c] = scv; t_s[2][c] = smv;
    __syncthreads();

    // ---- pointwise 1x1 projections: 157 outputs across 64 lanes ----
    for (int o = c; o < NF + NCC + NM; o += 64) {
        const float* wrow; const float* tv; float acc;
        if (o < NF)            { wrow = pwf_w + o * 64;            tv = t_s[0]; acc = pwf_b[o]; }
        else if (o < NF + NCC) { wrow = pwc_w + (o - NF) * 64;     tv = t_s[1]; acc = pwc_b[o - NF]; }
        else                   { wrow = pwm_w + (o - NF - NCC) * 64; tv = t_s[2]; acc = pwm_b[o - NF - NCC]; }
        #pragma unroll 8
        for (int k = 0; k < 64; ++k) acc = fmaf(wrow[k], tv[k], acc);
        if (o < NF + NCC) off_s[o] = acc;
        else              m_s[o - NF - NCC] = acc;
    }
    __syncthreads();

    // ---- gated softmax over the 52 scores ----
    float sp = m_s[NM - 1];
    float z = -INFINITY;
    if (c < NN) {
        float s  = m_s[c];
        float sg = 1.0f / (1.0f + expf(-((s - sp) / 0.1f)));
        z = s + logf(sg + 1e-10f);
    }
    float mx = z;
    #pragma unroll
    for (int o = 32; o >= 1; o >>= 1) mx = fmaxf(mx, __shfl_xor(mx, o));
    float e = (c < NN) ? expf(z - mx) : 0.0f;
    float ssum = e;
    #pragma unroll
    for (int o = 32; o >= 1; o >>= 1) ssum += __shfl_xor(ssum, o);
    if (c < NN) mod_s[c] = e / ssum;
    __syncthreads();

    // ---- 52-point bilinear sampling (zero padding) + modulation aggregate ----
    float agg = 0.0f;
    for (int n = 0; n < NN; ++n) {
        float modn = mod_s[n];
        float sx = (float)xw + p_n[n]      + off_s[n];
        float sy = (float)y  + p_n[NN + n] + off_s[NN + n];
        float x0 = floorf(sx), y0 = floorf(sy);
        float wx1 = sx - x0, wy1 = sy - y0;
        float wx0 = 1.0f - wx1, wy0 = 1.0f - wy1;
        float x1 = x0 + 1.0f, y1 = y0 + 1.0f;
        float acc4 = 0.0f;
        bool vx0 = (x0 >= 0.0f) && (x0 <= (float)(WW - 1));
        bool vx1 = (x1 >= 0.0f) && (x1 <= (float)(WW - 1));
        bool vy0 = (y0 >= 0.0f) && (y0 <= (float)(HH - 1));
        bool vy1 = (y1 >= 0.0f) && (y1 <= (float)(HH - 1));
        int xi0 = (int)fminf(fmaxf(x0, 0.0f), (float)(WW - 1));
        int xi1 = (int)fminf(fmaxf(x1, 0.0f), (float)(WW - 1));
        int yi0 = (int)fminf(fmaxf(y0, 0.0f), (float)(HH - 1));
        int yi1 = (int)fminf(fmaxf(y1, 0.0f), (float)(HH - 1));
        if (vy0 && vx0) acc4 = fmaf(wy0 * wx0, xtb[((size_t)(yi0 * WW + xi0)) * CC + c], acc4);
        if (vy0 && vx1) acc4 = fmaf(wy0 * wx1, xtb[((size_t)(yi0 * WW + xi1)) * CC + c], acc4);
        if (vy1 && vx0) acc4 = fmaf(wy1 * wx0, xtb[((size_t)(yi1 * WW + xi0)) * CC + c], acc4);
        if (vy1 && vx1) acc4 = fmaf(wy1 * wx1, xtb[((size_t)(yi1 * WW + xi1)) * CC + c], acc4);
        agg = fmaf(modn, acc4, agg);
    }

    // ---- pc 1x1 conv ----
    va[c] = agg;
    __syncthreads();
    float o1 = pc_b[c];
    #pragma unroll 8
    for (int k = 0; k < 64; ++k) o1 = fmaf(pc_w[c * 64 + k], va[k], o1);
    vb[c] = o1;
    __syncthreads();

    // ---- MLP layer 1 (relu) ----
    float h1 = mlp_b1[c];
    #pragma unroll 8
    for (int k = 0; k < 64; ++k) h1 = fmaf(mlp_w1[c * 64 + k], vb[k], h1);
    h1 = fmaxf(h1, 0.0f);
    va[c] = h1;
    __syncthreads();

    // ---- MLP layer 2 + residual ----
    float h2 = mlp_b2[c];
    #pragma unroll 8
    for (int k = 0; k < 64; ++k) h2 = fmaf(mlp_w2[c * 64 + k], va[k], h2);
    float res = h2 + xtb[((size_t)(y * WW + xw)) * CC + c];

    out[((size_t)(b * CC + c) * HH + y) * WW + xw] = res;
}

extern "C" void kernel_launch(void* const* d_in, const int* in_sizes, int n_in,
                              void* d_out, int out_size, void* d_ws, size_t ws_size,
                              hipStream_t stream) {
    const float* x     = (const float*)d_in[0];
    const float* p_n   = (const float*)d_in[1];
    const float* dwf_w = (const float*)d_in[2];
    const float* dwf_b = (const float*)d_in[3];
    const float* pwf_w = (const float*)d_in[4];
    const float* pwf_b = (const float*)d_in[5];
    const float* dwc_w = (const float*)d_in[6];
    const float* dwc_b = (const float*)d_in[7];
    const float* pwc_w = (const float*)d_in[8];
    const float* pwc_b = (const float*)d_in[9];
    const float* dwm_w = (const float*)d_in[10];
    const float* dwm_b = (const float*)d_in[11];
    const float* pwm_w = (const float*)d_in[12];
    const float* pwm_b = (const float*)d_in[13];
    const float* pc_w  = (const float*)d_in[14];
    const float* pc_b  = (const float*)d_in[15];
    const float* w1    = (const float*)d_in[16];
    const float* b1    = (const float*)d_in[17];
    const float* w2    = (const float*)d_in[18];
    const float* b2    = (const float*)d_in[19];

    float* xt   = (float*)d_ws;       // 4*64*64*64 floats = 4 MB NHWC copy of x
    float* outp = (float*)d_out;

    hipLaunchKernelGGL(transpose_kernel, dim3(BB * HH), dim3(256), 0, stream, x, xt);
    hipLaunchKernelGGL(crossd_main, dim3(BB * HH * WW), dim3(64), 0, stream,
                       xt, p_n,
                       dwf_w, dwf_b, pwf_w, pwf_b,
                       dwc_w, dwc_b, pwc_w, pwc_b,
                       dwm_w, dwm_b, pwm_w, pwm_b,
                       pc_w, pc_b, w1, b1, w2, b2, outp);
}

// Round 2
// 186.797 us; speedup vs baseline: 1.3156x; 1.3156x over previous
//
#include <hip/hip_runtime.h>
#include <cmath>

#define BB 4
#define HH 64
#define WW 64

#define COLS 65
#define TA 0                       // 64 x COLS : t-buffer / agg / h1
#define OFFB (64*COLS)             // 104 x COLS : offsets -> sx/sy
#define TB OFFB                    // 64 x COLS : pc output (overlaps OFF, live later)
#define MB (OFFB + 104*COLS)       // 53 x COLS : mask -> mod
#define POOL (MB + 53*COLS)        // 14365 floats = 57460 B

// ---------------- NCHW -> NHWC transpose (LDS tiled) ----------------
__global__ __launch_bounds__(256) void transpose_kernel(const float* __restrict__ x,
                                                        float* __restrict__ xt) {
    int bid = blockIdx.x;           // one block per (b, y) row
    int b = bid >> 6, y = bid & 63;
    __shared__ float tile[64][65];
    const float* xp = x + ((size_t)b * 64 * HH + y) * WW;
    #pragma unroll
    for (int k = 0; k < 16; ++k) {
        int idx = threadIdx.x + (k << 8);
        int c = idx >> 6, w = idx & 63;
        tile[c][w] = xp[(size_t)c * HH * WW + w];
    }
    __syncthreads();
    float* op = xt + ((size_t)(b * HH + y) * WW) * 64;
    #pragma unroll
    for (int k = 0; k < 16; ++k) {
        int idx = threadIdx.x + (k << 8);
        int w = idx >> 6, c = idx & 63;
        op[(size_t)w * 64 + c] = tile[c][w];
    }
}

// ---------------- fused main: 1 block (8 waves) per image row of 64 px ----------------
__global__ __launch_bounds__(512) void crossd_main(
    const float* __restrict__ xt, const float* __restrict__ x,
    const float* __restrict__ p_n,
    const float* __restrict__ dwf_w, const float* __restrict__ dwf_b,
    const float* __restrict__ pwf_w, const float* __restrict__ pwf_b,
    const float* __restrict__ dwc_w, const float* __restrict__ dwc_b,
    const float* __restrict__ pwc_w, const float* __restrict__ pwc_b,
    const float* __restrict__ dwm_w, const float* __restrict__ dwm_b,
    const float* __restrict__ pwm_w, const float* __restrict__ pwm_b,
    const float* __restrict__ pc_w, const float* __restrict__ pc_b,
    const float* __restrict__ w1, const float* __restrict__ b1,
    const float* __restrict__ w2, const float* __restrict__ b2,
    float* __restrict__ out)
{
    __shared__ float P[POOL];
    const int tid  = threadIdx.x;
    const int lane = tid & 63;
    const int wv   = __builtin_amdgcn_readfirstlane(tid >> 6);   // wave id 0..7
    const int b = blockIdx.x >> 6, y = blockIdx.x & 63;
    const float* xtb = xt + ((size_t)b * HH * WW) * 64;

    const float* dww[3] = {dwf_w, dwc_w, dwm_w};
    const float* dwb[3] = {dwf_b, dwc_b, dwm_b};
    const float* pww[3] = {pwf_w, pwc_w, pwm_w};
    const float* pwb[3] = {pwf_b, pwc_b, pwm_b};

    // ---- per-branch: depthwise 3x3 (lane=channel) then pointwise GEMM (lane=pixel) ----
    #pragma unroll
    for (int br = 0; br < 3; ++br) {
        const int R   = (br == 0) ? 32 : (br == 1) ? 72 : 53;
        const int RPW = (R + 7) >> 3;          // rows per wave (4 / 9 / 7)
        {   // depthwise: each wave covers 8 pixels, lane = channel
            const int c = lane;
            float wv9[9];
            #pragma unroll
            for (int k9 = 0; k9 < 9; ++k9) wv9[k9] = dww[br][c * 9 + k9];
            const float bias = dwb[br][c];
            #pragma unroll
            for (int i = 0; i < 8; ++i) {
                const int px = wv * 8 + i;
                float acc = bias;
                #pragma unroll
                for (int dy = 0; dy < 3; ++dy) {
                    int yy = y + dy - 1;
                    if (yy < 0 || yy >= HH) continue;
                    #pragma unroll
                    for (int dx = 0; dx < 3; ++dx) {
                        int xx = px + dx - 1;
                        if (xx < 0 || xx >= WW) continue;
                        acc = fmaf(xtb[(size_t)((yy << 6) + xx) * 64 + c], wv9[dy * 3 + dx], acc);
                    }
                }
                P[TA + c * COLS + px] = acc;
            }
        }
        __syncthreads();
        {   // pointwise GEMM: lane = pixel, wave owns RPW output rows, weights via s_load
            float acc[9];
            const int o0 = wv * RPW;
            #pragma unroll
            for (int r = 0; r < RPW; ++r) {
                int o = o0 + r; int oc = (o < R) ? o : (R - 1);
                acc[r] = pwb[br][oc];
            }
            #pragma unroll 8
            for (int k = 0; k < 64; ++k) {
                float v = P[TA + k * COLS + lane];
                #pragma unroll
                for (int r = 0; r < RPW; ++r) {
                    int o = o0 + r; int oc = (o < R) ? o : (R - 1);
                    acc[r] = fmaf(pww[br][oc * 64 + k], v, acc[r]);
                }
            }
            const int dbase = (br == 0) ? OFFB : (br == 1) ? (OFFB + 32 * COLS) : MB;
            #pragma unroll
            for (int r = 0; r < RPW; ++r) {
                int o = o0 + r;
                if (o < R) P[dbase + o * COLS + lane] = acc[r];
            }
        }
        __syncthreads();
    }

    // ---- gated softmax over 52 scores: lane = n, wave owns 8 pixels ----
    for (int i = 0; i < 8; ++i) {
        const int px = wv * 8 + i;
        const float sp = P[MB + 52 * COLS + px];
        float z = -1e30f;
        if (lane < 52) {
            float s  = P[MB + lane * COLS + px];
            float sg = 1.0f / (1.0f + expf(-(s - sp) * 10.0f));
            z = s + logf(sg + 1e-10f);
        }
        float mx = z;
        #pragma unroll
        for (int d = 32; d >= 1; d >>= 1) mx = fmaxf(mx, __shfl_xor(mx, d));
        float e = (lane < 52) ? expf(z - mx) : 0.0f;
        float sm = e;
        #pragma unroll
        for (int d = 32; d >= 1; d >>= 1) sm += __shfl_xor(sm, d);
        if (lane < 52) P[MB + lane * COLS + px] = e / sm;
    }

    // ---- absolute sample coords in-place: thread-parallel over (n, px) ----
    {
        const int px = tid & 63;
        for (int n = tid >> 6; n < 52; n += 8) {
            float sx = (float)px + p_n[n]      + P[OFFB + n * COLS + px];
            float sy = (float)y  + p_n[52 + n] + P[OFFB + (52 + n) * COLS + px];
            P[OFFB + n * COLS + px]        = sx;
            P[OFFB + (52 + n) * COLS + px] = sy;
        }
    }
    __syncthreads();

    // ---- 52-tap bilinear sampling + modulation: lane = channel, wave owns 8 px ----
    for (int i = 0; i < 8; ++i) {
        const int px = wv * 8 + i;
        float a = 0.0f;
        for (int n = 0; n < 52; ++n) {
            float sx = P[OFFB + n * COLS + px];
            float sy = P[OFFB + (52 + n) * COLS + px];
            float mo = P[MB + n * COLS + px];
            float x0f = floorf(sx), y0f = floorf(sy);
            float wx1 = sx - x0f, wy1 = sy - y0f;
            float wx0 = 1.0f - wx1, wy0 = 1.0f - wy1;
            int x0 = (int)x0f, y0 = (int)y0f;
            int xi0 = min(max(x0, 0), 63),     xi1 = min(max(x0 + 1, 0), 63);
            int yi0 = min(max(y0, 0), 63),     yi1 = min(max(y0 + 1, 0), 63);
            bool vx0 = (x0 >= 0)  & (x0 <= 63);
            bool vx1 = (x0 >= -1) & (x0 <= 62);
            bool vy0 = (y0 >= 0)  & (y0 <= 63);
            bool vy1 = (y0 >= -1) & (y0 <= 62);
            float s00 = (vy0 & vx0) ? xtb[(size_t)((yi0 << 6) + xi0) * 64 + lane] : 0.0f;
            float s01 = (vy0 & vx1) ? xtb[(size_t)((yi0 << 6) + xi1) * 64 + lane] : 0.0f;
            float s10 = (vy1 & vx0) ? xtb[(size_t)((yi1 << 6) + xi0) * 64 + lane] : 0.0f;
            float s11 = (vy1 & vx1) ? xtb[(size_t)((yi1 << 6) + xi1) * 64 + lane] : 0.0f;
            float t0 = fmaf(wx1, s01, wx0 * s00);
            float t1 = fmaf(wx1, s11, wx0 * s10);
            a = fmaf(mo, fmaf(wy1, t1, wy0 * t0), a);
        }
        P[TA + lane * COLS + px] = a;   // agg, stored transposed [c][px]
    }
    __syncthreads();

    // ---- pc 1x1 conv: TA -> TB (lane = pixel, 8 rows per wave) ----
    {
        float acc[8];
        const int o0 = wv * 8;
        #pragma unroll
        for (int r = 0; r < 8; ++r) acc[r] = pc_b[o0 + r];
        #pragma unroll 8
        for (int k = 0; k < 64; ++k) {
            float v = P[TA + k * COLS + lane];
            #pragma unroll
            for (int r = 0; r < 8; ++r) acc[r] = fmaf(pc_w[(o0 + r) * 64 + k], v, acc[r]);
        }
        #pragma unroll
        for (int r = 0; r < 8; ++r) P[TB + (o0 + r) * COLS + lane] = acc[r];
    }
    __syncthreads();

    // ---- mlp1 (relu): TB -> TA ----
    {
        float acc[8];
        const int o0 = wv * 8;
        #pragma unroll
        for (int r = 0; r < 8; ++r) acc[r] = b1[o0 + r];
        #pragma unroll 8
        for (int k = 0; k < 64; ++k) {
            float v = P[TB + k * COLS + lane];
            #pragma unroll
            for (int r = 0; r < 8; ++r) acc[r] = fmaf(w1[(o0 + r) * 64 + k], v, acc[r]);
        }
        #pragma unroll
        for (int r = 0; r < 8; ++r) P[TA + (o0 + r) * COLS + lane] = fmaxf(acc[r], 0.0f);
    }
    __syncthreads();

    // ---- mlp2 + residual + store (coalesced NCHW) ----
    {
        float acc[8];
        const int o0 = wv * 8;
        #pragma unroll
        for (int r = 0; r < 8; ++r) acc[r] = b2[o0 + r];
        #pragma unroll 8
        for (int k = 0; k < 64; ++k) {
            float v = P[TA + k * COLS + lane];
            #pragma unroll
            for (int r = 0; r < 8; ++r) acc[r] = fmaf(w2[(o0 + r) * 64 + k], v, acc[r]);
        }
        #pragma unroll
        for (int r = 0; r < 8; ++r) {
            int o = o0 + r;
            size_t idx = (((size_t)b * 64 + o) * 64 + y) * 64 + lane;
            out[idx] = acc[r] + x[idx];
        }
    }
}

extern "C" void kernel_launch(void* const* d_in, const int* in_sizes, int n_in,
                              void* d_out, int out_size, void* d_ws, size_t ws_size,
                              hipStream_t stream) {
    const float* x     = (const float*)d_in[0];
    const float* p_n   = (const float*)d_in[1];
    const float* dwf_w = (const float*)d_in[2];
    const float* dwf_b = (const float*)d_in[3];
    const float* pwf_w = (const float*)d_in[4];
    const float* pwf_b = (const float*)d_in[5];
    const float* dwc_w = (const float*)d_in[6];
    const float* dwc_b = (const float*)d_in[7];
    const float* pwc_w = (const float*)d_in[8];
    const float* pwc_b = (const float*)d_in[9];
    const float* dwm_w = (const float*)d_in[10];
    const float* dwm_b = (const float*)d_in[11];
    const float* pwm_w = (const float*)d_in[12];
    const float* pwm_b = (const float*)d_in[13];
    const float* pc_w  = (const float*)d_in[14];
    const float* pc_b  = (const float*)d_in[15];
    const float* w1    = (const float*)d_in[16];
    const float* b1    = (const float*)d_in[17];
    const float* w2    = (const float*)d_in[18];
    const float* b2    = (const float*)d_in[19];

    float* xt   = (float*)d_ws;       // 4 MB NHWC copy of x
    float* outp = (float*)d_out;

    hipLaunchKernelGGL(transpose_kernel, dim3(BB * HH), dim3(256), 0, stream, x, xt);
    hipLaunchKernelGGL(crossd_main, dim3(BB * HH), dim3(512), 0, stream,
                       xt, x, p_n,
                       dwf_w, dwf_b, pwf_w, pwf_b,
                       dwc_w, dwc_b, pwc_w, pwc_b,
                       dwm_w, dwm_b, pwm_w, pwm_b,
                       pc_w, pc_b, w1, b1, w2, b2, outp);
}

// Round 3
// 67.888 us; speedup vs baseline: 3.6200x; 2.7515x over previous
//
#include <hip/hip_runtime.h>
#include <cmath>

#define BB 4
#define HH 64
#define WW 64
#define COLS 65
#define TA 0                       // 64 x COLS : t-buffer / agg / h1
#define OFFB (64*COLS)             // 104 x COLS : offsets -> sx/sy
#define TB OFFB                    // 64 x COLS : pc output (overlaps OFFB, live later)
#define MB (OFFB + 104*COLS)       // 53 x COLS : mask -> mod
#define POOL (MB + 53*COLS)        // 14365 floats = 57460 B

// ---------------- NCHW -> NHWC transpose (LDS tiled) ----------------
__global__ __launch_bounds__(256) void transpose_kernel(const float* __restrict__ x,
                                                        float* __restrict__ xt) {
    int bid = blockIdx.x;
    int b = bid >> 6, y = bid & 63;
    __shared__ float tile[64][65];
    const float* xp = x + ((size_t)b * 64 * HH + y) * WW;
    #pragma unroll
    for (int k = 0; k < 16; ++k) {
        int idx = threadIdx.x + (k << 8);
        int c = idx >> 6, w = idx & 63;
        tile[c][w] = xp[(size_t)c * HH * WW + w];
    }
    __syncthreads();
    float* op = xt + ((size_t)(b * HH + y) * WW) * 64;
    #pragma unroll
    for (int k = 0; k < 16; ++k) {
        int idx = threadIdx.x + (k << 8);
        int w = idx >> 6, c = idx & 63;
        op[(size_t)w * 64 + c] = tile[c][w];
    }
}

// pointwise GEMM helper: lane = pixel, wave owns RPW consecutive output rows.
// o0 is wave-uniform -> W/B reads become scalar loads.
template<int RPW>
__device__ inline void pw_gemm(float* P, int lane, int o0, int R,
                               const float* __restrict__ W, const float* __restrict__ Bv,
                               int dbase) {
    int oc[RPW];
    float acc[RPW];
    #pragma unroll
    for (int r = 0; r < RPW; ++r) {
        oc[r] = min(o0 + r, R - 1);
        acc[r] = Bv[oc[r]];
    }
    #pragma unroll 8
    for (int k = 0; k < 64; ++k) {
        float v = P[TA + k * COLS + lane];
        #pragma unroll
        for (int r = 0; r < RPW; ++r)
            acc[r] = fmaf(W[oc[r] * 64 + k], v, acc[r]);
    }
    #pragma unroll
    for (int r = 0; r < RPW; ++r)
        if (o0 + r < R) P[dbase + (o0 + r) * COLS + lane] = acc[r];
}

// ---------------- fused main: 1 block (16 waves, 1024 thr) per image row ----------------
__global__ __launch_bounds__(1024) void crossd_main(
    const float* __restrict__ xt, const float* __restrict__ x,
    const float* __restrict__ p_n,
    const float* __restrict__ dwf_w, const float* __restrict__ dwf_b,
    const float* __restrict__ pwf_w, const float* __restrict__ pwf_b,
    const float* __restrict__ dwc_w, const float* __restrict__ dwc_b,
    const float* __restrict__ pwc_w, const float* __restrict__ pwc_b,
    const float* __restrict__ dwm_w, const float* __restrict__ dwm_b,
    const float* __restrict__ pwm_w, const float* __restrict__ pwm_b,
    const float* __restrict__ pc_w, const float* __restrict__ pc_b,
    const float* __restrict__ w1, const float* __restrict__ b1,
    const float* __restrict__ w2, const float* __restrict__ b2,
    float* __restrict__ out)
{
    __shared__ float P[POOL];
    const int tid  = threadIdx.x;
    const int lane = tid & 63;
    const int wv   = __builtin_amdgcn_readfirstlane(tid >> 6);   // 0..15
    const int b = blockIdx.x >> 6, y = blockIdx.x & 63;
    const float* xtb = xt + (size_t)b * (HH * WW * 64);

    // ---- fused depthwise 3x3 (all 3 branches share loads); wave owns 4 px, lane = ch ----
    float tc_r[4], tm_r[4];
    {
        const int c = lane;
        float wf9[9], wc9[9], wm9[9];
        #pragma unroll
        for (int k9 = 0; k9 < 9; ++k9) {
            wf9[k9] = dwf_w[c * 9 + k9];
            wc9[k9] = dwc_w[c * 9 + k9];
            wm9[k9] = dwm_w[c * 9 + k9];
        }
        const float bf = dwf_b[c], bc = dwc_b[c], bm = dwm_b[c];
        #pragma unroll
        for (int i = 0; i < 4; ++i) {
            const int px = wv * 4 + i;
            float af = bf, ac = bc, am = bm;
            #pragma unroll
            for (int dy = 0; dy < 3; ++dy) {
                int yy = y + dy - 1;
                if (yy < 0 || yy >= HH) continue;
                #pragma unroll
                for (int dx = 0; dx < 3; ++dx) {
                    int xx = px + dx - 1;
                    if (xx < 0 || xx >= WW) continue;
                    float v = xtb[(size_t)((yy << 6) + xx) * 64 + c];
                    int k = dy * 3 + dx;
                    af = fmaf(v, wf9[k], af);
                    ac = fmaf(v, wc9[k], ac);
                    am = fmaf(v, wm9[k], am);
                }
            }
            P[TA + c * COLS + px] = af;
            tc_r[i] = ac; tm_r[i] = am;
        }
    }
    __syncthreads();
    pw_gemm<2>(P, lane, wv * 2, 32, pwf_w, pwf_b, OFFB);             // f: 32 rows
    __syncthreads();
    #pragma unroll
    for (int i = 0; i < 4; ++i) P[TA + lane * COLS + wv * 4 + i] = tc_r[i];
    __syncthreads();
    pw_gemm<5>(P, lane, wv * 5, 72, pwc_w, pwc_b, OFFB + 32 * COLS); // c: 72 rows
    __syncthreads();
    #pragma unroll
    for (int i = 0; i < 4; ++i) P[TA + lane * COLS + wv * 4 + i] = tm_r[i];
    __syncthreads();
    pw_gemm<4>(P, lane, wv * 4, 53, pwm_w, pwm_b, MB);               // m: 53 rows
    __syncthreads();

    // ---- gated softmax over 52 scores: lane = n, wave owns 4 px ----
    #pragma unroll
    for (int i = 0; i < 4; ++i) {
        const int px = wv * 4 + i;
        const float sp = P[MB + 52 * COLS + px];
        float z = -1e30f;
        if (lane < 52) {
            float s  = P[MB + lane * COLS + px];
            float sg = 1.0f / (1.0f + __expf(-(s - sp) * 10.0f));
            z = s + __logf(sg + 1e-10f);
        }
        float mx = z;
        #pragma unroll
        for (int d = 32; d >= 1; d >>= 1) mx = fmaxf(mx, __shfl_xor(mx, d));
        float e = (lane < 52) ? __expf(z - mx) : 0.0f;
        float sm = e;
        #pragma unroll
        for (int d = 32; d >= 1; d >>= 1) sm += __shfl_xor(sm, d);
        if (lane < 52) P[MB + lane * COLS + px] = e / sm;
    }

    // ---- absolute sample coords in-place: threads parallel over (n, px) ----
    {
        const int px = tid & 63;
        for (int n = tid >> 6; n < 52; n += 16) {
            float sx = (float)px + p_n[n]      + P[OFFB + n * COLS + px];
            float sy = (float)y  + p_n[52 + n] + P[OFFB + (52 + n) * COLS + px];
            P[OFFB + n * COLS + px]        = sx;
            P[OFFB + (52 + n) * COLS + px] = sy;
        }
    }
    __syncthreads();

    // ---- 52-tap bilinear sampling: wave = 4 px, lane = (px_sub, ch_quad), float4 ----
    {
        const int sub = lane >> 4;         // 0..3
        const int c4  = lane & 15;         // channel quad
        const int px  = wv * 4 + sub;
        const float4* xt4 = reinterpret_cast<const float4*>(xtb);
        float4 agg = make_float4(0.f, 0.f, 0.f, 0.f);
        #pragma unroll 2
        for (int n = 0; n < 52; ++n) {
            float sx = P[OFFB + n * COLS + px];
            float sy = P[OFFB + (52 + n) * COLS + px];
            float mo = P[MB + n * COLS + px];
            float x0f = floorf(sx), y0f = floorf(sy);
            float wx1 = sx - x0f, wy1 = sy - y0f;
            float wx0 = 1.0f - wx1, wy0 = 1.0f - wy1;
            int x0 = (int)x0f, y0 = (int)y0f;
            int xi0 = min(max(x0, 0), 63), xi1 = min(max(x0 + 1, 0), 63);
            int yi0 = min(max(y0, 0), 63), yi1 = min(max(y0 + 1, 0), 63);
            bool vx0 = (x0 >= 0)  & (x0 <= 63);
            bool vx1 = (x0 >= -1) & (x0 <= 62);
            bool vy0 = (y0 >= 0)  & (y0 <= 63);
            bool vy1 = (y0 >= -1) & (y0 <= 62);
            float m00 = (vy0 & vx0) ? mo * wy0 * wx0 : 0.0f;
            float m01 = (vy0 & vx1) ? mo * wy0 * wx1 : 0.0f;
            float m10 = (vy1 & vx0) ? mo * wy1 * wx0 : 0.0f;
            float m11 = (vy1 & vx1) ? mo * wy1 * wx1 : 0.0f;
            float4 s00 = xt4[((yi0 << 6) + xi0) * 16 + c4];
            float4 s01 = xt4[((yi0 << 6) + xi1) * 16 + c4];
            float4 s10 = xt4[((yi1 << 6) + xi0) * 16 + c4];
            float4 s11 = xt4[((yi1 << 6) + xi1) * 16 + c4];
            agg.x = fmaf(m00, s00.x, agg.x); agg.y = fmaf(m00, s00.y, agg.y);
            agg.z = fmaf(m00, s00.z, agg.z); agg.w = fmaf(m00, s00.w, agg.w);
            agg.x = fmaf(m01, s01.x, agg.x); agg.y = fmaf(m01, s01.y, agg.y);
            agg.z = fmaf(m01, s01.z, agg.z); agg.w = fmaf(m01, s01.w, agg.w);
            agg.x = fmaf(m10, s10.x, agg.x); agg.y = fmaf(m10, s10.y, agg.y);
            agg.z = fmaf(m10, s10.z, agg.z); agg.w = fmaf(m10, s10.w, agg.w);
            agg.x = fmaf(m11, s11.x, agg.x); agg.y = fmaf(m11, s11.y, agg.y);
            agg.z = fmaf(m11, s11.z, agg.z); agg.w = fmaf(m11, s11.w, agg.w);
        }
        __syncthreads();   // all waves done reading TA (t_m) before agg overwrite
        P[TA + (c4 * 4 + 0) * COLS + px] = agg.x;
        P[TA + (c4 * 4 + 1) * COLS + px] = agg.y;
        P[TA + (c4 * 4 + 2) * COLS + px] = agg.z;
        P[TA + (c4 * 4 + 3) * COLS + px] = agg.w;
    }
    __syncthreads();

    // ---- pc 1x1: TA -> TB ----
    pw_gemm<4>(P, lane, wv * 4, 64, pc_w, pc_b, TB);
    __syncthreads();

    // ---- mlp1 (relu): TB -> TA ----
    {
        const int o0 = wv * 4;
        float acc[4];
        #pragma unroll
        for (int r = 0; r < 4; ++r) acc[r] = b1[o0 + r];
        #pragma unroll 8
        for (int k = 0; k < 64; ++k) {
            float v = P[TB + k * COLS + lane];
            #pragma unroll
            for (int r = 0; r < 4; ++r) acc[r] = fmaf(w1[(o0 + r) * 64 + k], v, acc[r]);
        }
        __syncthreads();   // TA (agg) fully consumed by pc before overwrite
        #pragma unroll
        for (int r = 0; r < 4; ++r) P[TA + (o0 + r) * COLS + lane] = fmaxf(acc[r], 0.0f);
    }
    __syncthreads();

    // ---- mlp2 + residual + coalesced NCHW store ----
    {
        const int o0 = wv * 4;
        float acc[4];
        #pragma unroll
        for (int r = 0; r < 4; ++r) acc[r] = b2[o0 + r];
        #pragma unroll 8
        for (int k = 0; k < 64; ++k) {
            float v = P[TA + k * COLS + lane];
            #pragma unroll
            for (int r = 0; r < 4; ++r) acc[r] = fmaf(w2[(o0 + r) * 64 + k], v, acc[r]);
        }
        #pragma unroll
        for (int r = 0; r < 4; ++r) {
            int o = o0 + r;
            size_t idx = (((size_t)b * 64 + o) * 64 + y) * 64 + lane;
            out[idx] = acc[r] + x[idx];
        }
    }
}

extern "C" void kernel_launch(void* const* d_in, const int* in_sizes, int n_in,
                              void* d_out, int out_size, void* d_ws, size_t ws_size,
                              hipStream_t stream) {
    const float* x     = (const float*)d_in[0];
    const float* p_n   = (const float*)d_in[1];
    const float* dwf_w = (const float*)d_in[2];
    const float* dwf_b = (const float*)d_in[3];
    const float* pwf_w = (const float*)d_in[4];
    const float* pwf_b = (const float*)d_in[5];
    const float* dwc_w = (const float*)d_in[6];
    const float* dwc_b = (const float*)d_in[7];
    const float* pwc_w = (const float*)d_in[8];
    const float* pwc_b = (const float*)d_in[9];
    const float* dwm_w = (const float*)d_in[10];
    const float* dwm_b = (const float*)d_in[11];
    const float* pwm_w = (const float*)d_in[12];
    const float* pwm_b = (const float*)d_in[13];
    const float* pc_w  = (const float*)d_in[14];
    const float* pc_b  = (const float*)d_in[15];
    const float* w1    = (const float*)d_in[16];
    const float* b1    = (const float*)d_in[17];
    const float* w2    = (const float*)d_in[18];
    const float* b2    = (const float*)d_in[19];

    float* xt   = (float*)d_ws;       // 4 MB NHWC copy of x
    float* outp = (float*)d_out;

    hipLaunchKernelGGL(transpose_kernel, dim3(BB * HH), dim3(256), 0, stream, x, xt);
    hipLaunchKernelGGL(crossd_main, dim3(BB * HH), dim3(1024), 0, stream,
                       xt, x, p_n,
                       dwf_w, dwf_b, pwf_w, pwf_b,
                       dwc_w, dwc_b, pwc_w, pwc_b,
                       dwm_w, dwm_b, pwm_w, pwm_b,
                       pc_w, pc_b, w1, b1, w2, b2, outp);
}